// Round 5
// baseline (196.081 us; speedup 1.0000x reference)
//
#include <hip/hip_runtime.h>

typedef _Float16 half8  __attribute__((ext_vector_type(8)));
typedef _Float16 half4v __attribute__((ext_vector_type(4)));
typedef float f32x4 __attribute__((ext_vector_type(4)));
typedef int int4v __attribute__((ext_vector_type(4)));

#define M_DIM 8192
#define D_DIM 768
#define H_DIM 3072

// ---- workspace byte offsets (max ~139 MB) ----
#define WS_WSCALE2   16
#define WS_BINT1     (WS_WSCALE2 + 768*4)
#define WS_BSCALE1   (WS_BINT1 + 3072*4)
#define WS_BINT2     (WS_BSCALE1 + 3072*4)
#define WS_BSCALE2   (WS_BINT2 + 768*4)
#define WS_XQ        34560UL
#define WS_WQ1       (WS_XQ  + (size_t)M_DIM*D_DIM*2)            // f16 W1 ints
#define WS_WQ2I      (WS_WQ1 + (size_t)H_DIM*D_DIM*2)            // int8 W2 ints
#define WS_H1        (WS_WQ2I + (size_t)D_DIM*H_DIM)             // f32 fc1 out (100MB)
#define WS_Q2        WS_H1                                       // alias: h1 dead after k4
#define WS_H2        (WS_H1 + (size_t)M_DIM*H_DIM)               // f32 fc2 out, inside old h1
#define WS_Q1        (WS_H1 + (size_t)M_DIM*H_DIM*4)             // int8 q1 (25MB)

// ---------- helpers ----------
__device__ __forceinline__ void gl_lds16(const _Float16* g, _Float16* l) {
  __builtin_amdgcn_global_load_lds(
      (const __attribute__((address_space(1))) void*)g,
      (__attribute__((address_space(3))) void*)l, 16, 0, 0);
}
__device__ __forceinline__ void gl_lds16c(const char* g, char* l) {
  __builtin_amdgcn_global_load_lds(
      (const __attribute__((address_space(1))) void*)g,
      (__attribute__((address_space(3))) void*)l, 16, 0, 0);
}

struct GeluP { float scale1, bintg, cintg, shiftint, s_out; };

__device__ __forceinline__ GeluP gelu_params(float max1) {
  GeluP p;
  p.scale1 = fmaxf(max1, 1e-8f) / 127.0f;
  float se = p.scale1 / 1.4142f;
  p.bintg = floorf(-1.769f / se);
  p.cintg = floorf(((float)(1.0 / -0.2888)) / (se * se));
  float se2 = ((se * se) * -0.2888f) * 16384.0f;
  p.shiftint = floorf(1.0f / se2);
  p.s_out = (p.scale1 * se2) * 0.5f;
  return p;
}

__device__ __forceinline__ float gelu_val(const GeluP& p, float qf) {
  float sg = (qf > 0.f) ? 1.f : ((qf < 0.f) ? -1.f : 0.f);
  float aq = fminf(fabsf(qf), -p.bintg);
  float t = aq + p.bintg;
  float y = sg * (t * t + p.cintg);
  float yf = floorf(y * (1.0f / 16384.0f));
  return (qf * (yf + p.shiftint)) * p.s_out;
}

// ---------- k1: weight quantization (W1 -> f16 ints, W2 -> int8), zero ws scalars ----------
__global__ __launch_bounds__(256)
void k1_prep(const float* __restrict__ W1, const float* __restrict__ b1,
             const float* __restrict__ W2, const float* __restrict__ sxp,
             _Float16* __restrict__ wq1, char* __restrict__ wq2i,
             float* __restrict__ wscale2, float* __restrict__ bint1,
             float* __restrict__ bscale1, unsigned* __restrict__ wsu)
{
  if (blockIdx.x == 0 && threadIdx.x == 0) { wsu[0] = 0u; wsu[1] = 0u; wsu[2] = 0u; }
  int w = blockIdx.x * 4 + (threadIdx.x >> 6);   // one wave per output row
  int lane = threadIdx.x & 63;
  if (w < H_DIM) {            // W1: 3072 rows, K=768
    const float* row = W1 + (size_t)w * D_DIM;
    f32x4 v[3]; float m = 0.f;
#pragma unroll
    for (int t = 0; t < 3; t++) {
      v[t] = *(const f32x4*)(row + t * 256 + lane * 4);
#pragma unroll
      for (int j = 0; j < 4; j++) m = fmaxf(m, fabsf(v[t][j]));
    }
#pragma unroll
    for (int off = 32; off >= 1; off >>= 1) m = fmaxf(m, __shfl_xor(m, off));
    float wsc = fmaxf(m, 1e-8f) / 127.0f;
    _Float16* orow = wq1 + (size_t)w * D_DIM;
#pragma unroll
    for (int t = 0; t < 3; t++) {
      half4v h;
#pragma unroll
      for (int j = 0; j < 4; j++) {
        float q = fminf(fmaxf(rintf(v[t][j] / wsc), -128.f), 127.f);
        h[j] = (_Float16)q;
      }
      *(half4v*)(orow + t * 256 + lane * 4) = h;
    }
    if (lane == 0) {
      float bs = wsc * sxp[0];
      bint1[w] = rintf(b1[w] / bs);
      bscale1[w] = bs;
    }
  } else {                    // W2: 768 rows, K=3072 -> int8
    int o = w - H_DIM;
    const float* row = W2 + (size_t)o * H_DIM;
    f32x4 v[12]; float m = 0.f;
#pragma unroll
    for (int t = 0; t < 12; t++) {
      v[t] = *(const f32x4*)(row + t * 256 + lane * 4);
#pragma unroll
      for (int j = 0; j < 4; j++) m = fmaxf(m, fabsf(v[t][j]));
    }
#pragma unroll
    for (int off = 32; off >= 1; off >>= 1) m = fmaxf(m, __shfl_xor(m, off));
    float wsc = fmaxf(m, 1e-8f) / 127.0f;
    unsigned* orow = (unsigned*)(wq2i + (size_t)o * H_DIM);
#pragma unroll
    for (int t = 0; t < 12; t++) {
      unsigned pk = 0;
#pragma unroll
      for (int j = 0; j < 4; j++) {
        float q = fminf(fmaxf(rintf(v[t][j] / wsc), -128.f), 127.f);
        pk |= ((unsigned)(unsigned char)(char)(int)q) << (8 * j);
      }
      orow[t * 64 + lane] = pk;
    }
    if (lane == 0) wscale2[o] = wsc;
  }
}

// ---------- k2: x -> f16 integer activations ----------
__global__ __launch_bounds__(256)
void k2_quant_x(const float* __restrict__ x, const float* __restrict__ sxp,
                _Float16* __restrict__ xq, int n4)
{
  float sx = sxp[0];
  int stride = gridDim.x * blockDim.x;
  for (int i = blockIdx.x * blockDim.x + threadIdx.x; i < n4; i += stride) {
    f32x4 v = ((const f32x4*)x)[i];
    half4v h;
#pragma unroll
    for (int j = 0; j < 4; j++) h[j] = (_Float16)(v[j] / sx);
    ((half4v*)xq)[i] = h;
  }
}

// ---------- fc1 GEMM, occupancy-first deep pipeline ----------
// 128x128 tile, BK=32, 4 waves (2x2 of 64x64), triple-buffered 48KB LDS
// (-> 3 blocks/CU), counted vmcnt, chunk-XOR swizzle, setprio.
#define F16_SLOT 8192   // halfs per slot: A 128x32 (4096) + B 128x32 (4096)

__global__ __launch_bounds__(256)
void gemm_f16_dp(const _Float16* __restrict__ A, const _Float16* __restrict__ B,
                 const float* __restrict__ bint, const float* __restrict__ bscale,
                 float* __restrict__ C, unsigned* __restrict__ maxw, int N, int K)
{
  __shared__ _Float16 lds[3 * F16_SLOT];
  __shared__ float wred[4];
  const int tid = threadIdx.x;
  const int wid = tid >> 6;
  const int lane = tid & 63;
  const int m0 = blockIdx.x * 128;
  const int n0 = blockIdx.y * 128;
  const int wm = wid >> 1;             // 0..1
  const int wn = wid & 1;              // 0..1

  // staging source (swizzle folded into global address; +64-row loads keep
  // the same XOR since ((r+64)>>1)&3 == (r>>1)&3)
  const int sr = tid >> 2;             // 0..63
  const int sc = tid & 3;              // 16B chunk in 64B row
  const int csw = sc ^ ((sr >> 1) & 3);
  const _Float16* pa0 = A + (size_t)(m0 + sr) * K + csw * 8;
  const _Float16* pa1 = A + (size_t)(m0 + 64 + sr) * K + csw * 8;
  const _Float16* pb0 = B + (size_t)(n0 + sr) * K + csw * 8;
  const _Float16* pb1 = B + (size_t)(n0 + 64 + sr) * K + csw * 8;

#define STAGE_F(t, s) do {                                                   \
    _Float16* const base = lds + (s) * F16_SLOT + wid * 512;                 \
    gl_lds16(pa0 + (size_t)(t) * 32, base);                                  \
    gl_lds16(pa1 + (size_t)(t) * 32, base + 2048);                           \
    gl_lds16(pb0 + (size_t)(t) * 32, base + 4096);                           \
    gl_lds16(pb1 + (size_t)(t) * 32, base + 6144);                           \
  } while (0)

  // fragment read byte offsets (same XOR on the read side)
  int aoff[4], boff[4];
  const int ks = lane >> 4;
#pragma unroll
  for (int f = 0; f < 4; f++) {
    int r = wm * 64 + f * 16 + (lane & 15);
    aoff[f] = r * 64 + ((ks ^ ((r >> 1) & 3)) * 16);
    int rn = wn * 64 + f * 16 + (lane & 15);
    boff[f] = 8192 + rn * 64 + ((ks ^ ((rn >> 1) & 3)) * 16);
  }

  f32x4 acc[4][4];
#pragma unroll
  for (int i = 0; i < 4; i++)
#pragma unroll
    for (int j = 0; j < 4; j++) acc[i][j] = (f32x4){0.f, 0.f, 0.f, 0.f};

  const int nt = K / 32;
  STAGE_F(0, 0);
  STAGE_F(1, 1);
  for (int t = 0; t < nt; ++t) {
    const int s = t % 3;
    if (t + 1 < nt) asm volatile("s_waitcnt vmcnt(4)" ::: "memory");
    else            asm volatile("s_waitcnt vmcnt(0)" ::: "memory");
    asm volatile("s_barrier" ::: "memory");
    if (t + 2 < nt) STAGE_F(t + 2, (t + 2) % 3);
    const char* sb = (const char*)(lds + s * F16_SLOT);
    half8 a[4], b01[2], b23[2];
#pragma unroll
    for (int f = 0; f < 4; f++) a[f] = *(const half8*)(sb + aoff[f]);
    b01[0] = *(const half8*)(sb + boff[0]);
    b01[1] = *(const half8*)(sb + boff[1]);
    __builtin_amdgcn_s_setprio(1);
#pragma unroll
    for (int i = 0; i < 4; i++)
#pragma unroll
      for (int j = 0; j < 2; j++)
        acc[i][j] = __builtin_amdgcn_mfma_f32_16x16x32_f16(a[i], b01[j], acc[i][j], 0, 0, 0);
    __builtin_amdgcn_s_setprio(0);
    b23[0] = *(const half8*)(sb + boff[2]);
    b23[1] = *(const half8*)(sb + boff[3]);
    __builtin_amdgcn_s_setprio(1);
#pragma unroll
    for (int i = 0; i < 4; i++)
#pragma unroll
      for (int j = 0; j < 2; j++)
        acc[i][j + 2] = __builtin_amdgcn_mfma_f32_16x16x32_f16(a[i], b23[j], acc[i][j + 2], 0, 0, 0);
    __builtin_amdgcn_s_setprio(0);
  }
#undef STAGE_F

  float tmax = 0.f;
  const int orow0 = m0 + wm * 64 + (lane >> 4) * 4;
  const int ocol0 = n0 + wn * 64 + (lane & 15);
#pragma unroll
  for (int j = 0; j < 4; j++) {
    const int col = ocol0 + j * 16;
    const float bi = bint[col];
    const float bs = bscale[col];
#pragma unroll
    for (int i = 0; i < 4; i++) {
#pragma unroll
      for (int e = 0; e < 4; e++) {
        const int rowm = orow0 + i * 16 + e;
        float v = (acc[i][j][e] + bi) * bs;
        C[(size_t)rowm * N + col] = v;
        tmax = fmaxf(tmax, fabsf(v));
      }
    }
  }
#pragma unroll
  for (int off = 32; off >= 1; off >>= 1) tmax = fmaxf(tmax, __shfl_xor(tmax, off));
  if (lane == 0) wred[wid] = tmax;
  __syncthreads();
  if (tid == 0) {
    float bm = fmaxf(fmaxf(wred[0], wred[1]), fmaxf(wred[2], wred[3]));
    atomicMax(maxw, __float_as_uint(bm));
  }
}

// ---------- k4: 8-bit requant of h1 + inline IntGELU for max2 ----------
__global__ __launch_bounds__(256)
void k4_gelu(const float* __restrict__ h1, const unsigned* __restrict__ wsu,
             char* __restrict__ q1, unsigned* __restrict__ maxw, int n4)
{
  GeluP p = gelu_params(__uint_as_float(wsu[0]));
  float tmax = 0.f;
  int stride = gridDim.x * blockDim.x;
  for (int i = blockIdx.x * blockDim.x + threadIdx.x; i < n4; i += stride) {
    f32x4 h = ((const f32x4*)h1)[i];
    unsigned pack = 0;
#pragma unroll
    for (int j = 0; j < 4; j++) {
      float qf = fminf(fmaxf(rintf(h[j] / p.scale1), -128.f), 127.f);
      tmax = fmaxf(tmax, fabsf(gelu_val(p, qf)));
      pack |= ((unsigned)(unsigned char)(char)(int)qf) << (8 * j);
    }
    ((unsigned*)q1)[i] = pack;
  }
#pragma unroll
  for (int off = 32; off >= 1; off >>= 1) tmax = fmaxf(tmax, __shfl_xor(tmax, off));
  __shared__ float wred[4];
  int wid = threadIdx.x >> 6;
  if ((threadIdx.x & 63) == 0) wred[wid] = tmax;
  __syncthreads();
  if (threadIdx.x == 0) {
    float bm = fmaxf(fmaxf(wred[0], wred[1]), fmaxf(wred[2], wred[3]));
    atomicMax(maxw, __float_as_uint(bm));
  }
}

// ---------- k6: fc2 bias quantization (needs max2) ----------
__global__ __launch_bounds__(256)
void k6_bias(const unsigned* __restrict__ wsu, const float* __restrict__ wscale2,
             const float* __restrict__ b2, float* __restrict__ bint2,
             float* __restrict__ bscale2)
{
  float scale2 = fmaxf(__uint_as_float(wsu[1]), 1e-8f) / 127.0f;
  for (int o = threadIdx.x; o < D_DIM; o += 256) {
    float bs = wscale2[o] * scale2;
    bint2[o] = rintf(b2[o] / bs);
    bscale2[o] = bs;
  }
}

// ---------- k5: q1 -> q2 (int8 GELU+requant, arithmetic) ----------
__global__ __launch_bounds__(256)
void k5_q2(const char* __restrict__ q1, const unsigned* __restrict__ wsu,
           char* __restrict__ q2, int n16)
{
  GeluP p = gelu_params(__uint_as_float(wsu[0]));
  float scale2 = fmaxf(__uint_as_float(wsu[1]), 1e-8f) / 127.0f;
  int stride = gridDim.x * blockDim.x;
  for (int i = blockIdx.x * blockDim.x + threadIdx.x; i < n16; i += stride) {
    uint4 pk = ((const uint4*)q1)[i];
    uint4 o;
    unsigned* pw[4] = {&o.x, &o.y, &o.z, &o.w};
    unsigned pr[4] = {pk.x, pk.y, pk.z, pk.w};
#pragma unroll
    for (int w = 0; w < 4; w++) {
      unsigned acc = 0;
#pragma unroll
      for (int j = 0; j < 4; j++) {
        float qf = (float)(int)(signed char)(pr[w] >> (8 * j));
        float g = gelu_val(p, qf);
        float q2f = fminf(fmaxf(rintf(g / scale2), -128.f), 127.f);
        acc |= ((unsigned)(unsigned char)(char)(int)q2f) << (8 * j);
      }
      *pw[w] = acc;
    }
    ((uint4*)q2)[i] = o;
  }
}

// ---------- fc2 GEMM: int8 MFMA 16x16x64, occupancy-first deep pipeline ----------
// 64x128 tile, BK=64, 4 waves (2x2 of 32x64), triple-buffered 36KB LDS
// (-> 4 blocks/CU), counted vmcnt(3), chunk-XOR swizzle.
#define I8_SLOT 12288   // bytes: A 64x64 (4096) + B 128x64 (8192)

__global__ __launch_bounds__(256)
void gemm_i8_dp(const char* __restrict__ A, const char* __restrict__ B,
                const float* __restrict__ bint, const float* __restrict__ bscale,
                float* __restrict__ C, unsigned* __restrict__ maxw, int N, int K)
{
  __shared__ char lds[3 * I8_SLOT];
  __shared__ float wred[4];
  const int tid = threadIdx.x;
  const int wid = tid >> 6;
  const int lane = tid & 63;
  const int m0 = blockIdx.x * 64;
  const int n0 = blockIdx.y * 128;
  const int wm = wid >> 1;             // 0..1
  const int wn = wid & 1;              // 0..1

  const int sr = tid >> 2;             // 0..63
  const int sc = tid & 3;              // 16B chunk in 64B row
  const int csw = sc ^ ((sr >> 1) & 3);
  const char* pa  = A + (size_t)(m0 + sr) * K + csw * 16;
  const char* pb0 = B + (size_t)(n0 + sr) * K + csw * 16;
  const char* pb1 = B + (size_t)(n0 + 64 + sr) * K + csw * 16;

#define STAGE_I(t, s) do {                                                   \
    char* const base = lds + (s) * I8_SLOT + wid * 1024;                     \
    gl_lds16c(pa  + (size_t)(t) * 64, base);                                 \
    gl_lds16c(pb0 + (size_t)(t) * 64, base + 4096);                          \
    gl_lds16c(pb1 + (size_t)(t) * 64, base + 8192);                          \
  } while (0)

  int aoff[2], boff[4];
  const int ks = lane >> 4;
#pragma unroll
  for (int f = 0; f < 2; f++) {
    int r = wm * 32 + f * 16 + (lane & 15);
    aoff[f] = r * 64 + ((ks ^ ((r >> 1) & 3)) * 16);
  }
#pragma unroll
  for (int f = 0; f < 4; f++) {
    int rn = wn * 64 + f * 16 + (lane & 15);
    boff[f] = 4096 + rn * 64 + ((ks ^ ((rn >> 1) & 3)) * 16);
  }

  int4v acc[2][4];
#pragma unroll
  for (int i = 0; i < 2; i++)
#pragma unroll
    for (int j = 0; j < 4; j++) acc[i][j] = (int4v){0, 0, 0, 0};

  const int nt = K / 64;
  STAGE_I(0, 0);
  STAGE_I(1, 1);
  for (int t = 0; t < nt; ++t) {
    const int s = t % 3;
    if (t + 1 < nt) asm volatile("s_waitcnt vmcnt(3)" ::: "memory");
    else            asm volatile("s_waitcnt vmcnt(0)" ::: "memory");
    asm volatile("s_barrier" ::: "memory");
    if (t + 2 < nt) STAGE_I(t + 2, (t + 2) % 3);
    const char* sb = lds + s * I8_SLOT;
    int4v a[2], b01[2], b23[2];
#pragma unroll
    for (int f = 0; f < 2; f++) a[f] = *(const int4v*)(sb + aoff[f]);
    b01[0] = *(const int4v*)(sb + boff[0]);
    b01[1] = *(const int4v*)(sb + boff[1]);
    __builtin_amdgcn_s_setprio(1);
#pragma unroll
    for (int i = 0; i < 2; i++)
#pragma unroll
      for (int j = 0; j < 2; j++)
        acc[i][j] = __builtin_amdgcn_mfma_i32_16x16x64_i8(a[i], b01[j], acc[i][j], 0, 0, 0);
    __builtin_amdgcn_s_setprio(0);
    b23[0] = *(const int4v*)(sb + boff[2]);
    b23[1] = *(const int4v*)(sb + boff[3]);
    __builtin_amdgcn_s_setprio(1);
#pragma unroll
    for (int i = 0; i < 2; i++)
#pragma unroll
      for (int j = 0; j < 2; j++)
        acc[i][j + 2] = __builtin_amdgcn_mfma_i32_16x16x64_i8(a[i], b23[j], acc[i][j + 2], 0, 0, 0);
    __builtin_amdgcn_s_setprio(0);
  }
#undef STAGE_I

  float tmax = 0.f;
  const int orow0 = m0 + wm * 32 + (lane >> 4) * 4;
  const int ocol0 = n0 + wn * 64 + (lane & 15);
#pragma unroll
  for (int j = 0; j < 4; j++) {
    const int col = ocol0 + j * 16;
    const float bi = bint[col];
    const float bs = bscale[col];
#pragma unroll
    for (int i = 0; i < 2; i++) {
#pragma unroll
      for (int e = 0; e < 4; e++) {
        const int rowm = orow0 + i * 16 + e;
        float v = ((float)acc[i][j][e] + bi) * bs;
        C[(size_t)rowm * N + col] = v;
        tmax = fmaxf(tmax, fabsf(v));
      }
    }
  }
#pragma unroll
  for (int off = 32; off >= 1; off >>= 1) tmax = fmaxf(tmax, __shfl_xor(tmax, off));
  if (lane == 0) wred[wid] = tmax;
  __syncthreads();
  if (tid == 0) {
    float bm = fmaxf(fmaxf(wred[0], wred[1]), fmaxf(wred[2], wred[3]));
    atomicMax(maxw, __float_as_uint(bm));
  }
}

// ---------- k7: 16-bit requant of h2 -> output (+ scale scalar) ----------
__global__ __launch_bounds__(256)
void k7_final(const float* __restrict__ h2, const unsigned* __restrict__ wsu,
              float* __restrict__ out, int n4, int ntot)
{
  float scale16 = fmaxf(__uint_as_float(wsu[2]), 1e-8f) / 32767.0f;
  int stride = gridDim.x * blockDim.x;
  for (int i = blockIdx.x * blockDim.x + threadIdx.x; i < n4; i += stride) {
    f32x4 v = ((const f32x4*)h2)[i];
    f32x4 o;
#pragma unroll
    for (int j = 0; j < 4; j++) {
      float q = fminf(fmaxf(rintf(v[j] / scale16), -32768.f), 32767.f);
      o[j] = q * scale16;
    }
    ((f32x4*)out)[i] = o;
  }
  if (blockIdx.x == 0 && threadIdx.x == 0) out[ntot] = scale16;
}

extern "C" void kernel_launch(void* const* d_in, const int* in_sizes, int n_in,
                              void* d_out, int out_size, void* d_ws, size_t ws_size,
                              hipStream_t stream)
{
  (void)in_sizes; (void)n_in; (void)out_size; (void)ws_size;
  const float* x  = (const float*)d_in[0];
  const float* sx = (const float*)d_in[1];
  const float* W1 = (const float*)d_in[2];
  const float* b1 = (const float*)d_in[3];
  const float* W2 = (const float*)d_in[4];
  const float* b2 = (const float*)d_in[5];
  float* out = (float*)d_out;
  char* ws = (char*)d_ws;

  unsigned* wsu   = (unsigned*)ws;                 // [0]=max1 [1]=max2 [2]=max3
  float* wscale2  = (float*)(ws + WS_WSCALE2);
  float* bint1    = (float*)(ws + WS_BINT1);
  float* bscale1  = (float*)(ws + WS_BSCALE1);
  float* bint2    = (float*)(ws + WS_BINT2);
  float* bscale2  = (float*)(ws + WS_BSCALE2);
  _Float16* xq    = (_Float16*)(ws + WS_XQ);
  _Float16* wq1   = (_Float16*)(ws + WS_WQ1);
  char* wq2i      = (char*)(ws + WS_WQ2I);
  float* h1       = (float*)(ws + WS_H1);
  char* q2        = (char*)(ws + WS_Q2);
  float* h2       = (float*)(ws + WS_H2);
  char* q1        = (char*)(ws + WS_Q1);

  k1_prep<<<dim3(960), dim3(256), 0, stream>>>(W1, b1, W2, sx, wq1, wq2i, wscale2, bint1, bscale1, wsu);
  k2_quant_x<<<dim3(2048), dim3(256), 0, stream>>>(x, sx, xq, (M_DIM * D_DIM) / 4);
  gemm_f16_dp<<<dim3(64, 24), dim3(256), 0, stream>>>(xq, wq1, bint1, bscale1, h1, wsu + 0, H_DIM, D_DIM);
  k4_gelu<<<dim3(2048), dim3(256), 0, stream>>>(h1, wsu, q1, wsu + 1, (M_DIM * H_DIM) / 4);
  k6_bias<<<dim3(1), dim3(256), 0, stream>>>(wsu, wscale2, b2, bint2, bscale2);
  k5_q2<<<dim3(2048), dim3(256), 0, stream>>>(q1, wsu, q2, (M_DIM * H_DIM) / 16);
  gemm_i8_dp<<<dim3(128, 6), dim3(256), 0, stream>>>(q2, wq2i, bint2, bscale2, h2, wsu + 2, D_DIM, H_DIM);
  k7_final<<<dim3(2048), dim3(256), 0, stream>>>(h2, wsu, out, (M_DIM * D_DIM) / 4, M_DIM * D_DIM);
}

// Round 6
// 178.685 us; speedup vs baseline: 1.0974x; 1.0974x over previous
//
#include <hip/hip_runtime.h>

typedef _Float16 half8  __attribute__((ext_vector_type(8)));
typedef _Float16 half4v __attribute__((ext_vector_type(4)));
typedef float f32x4 __attribute__((ext_vector_type(4)));
typedef int int4v __attribute__((ext_vector_type(4)));

#define M_DIM 8192
#define D_DIM 768
#define H_DIM 3072

// ---- workspace byte offsets ----
#define WS_WSCALE2   16
#define WS_BINT1     (WS_WSCALE2 + 768*4)
#define WS_BSCALE1   (WS_BINT1 + 3072*4)
#define WS_XQ        34560UL
#define WS_WQ1       (WS_XQ  + (size_t)M_DIM*D_DIM*2)            // f16 W1 ints
#define WS_WQ2I      (WS_WQ1 + (size_t)H_DIM*D_DIM*2)            // int8 W2 ints
#define WS_H1        (WS_WQ2I + (size_t)D_DIM*H_DIM)             // f32 fc1 out (100MB)
#define WS_H2        (WS_H1 + (size_t)M_DIM*H_DIM)               // f32 fc2 out, inside old h1
#define WS_Q1        (WS_H1 + (size_t)M_DIM*H_DIM*4)             // int8 q1 (25MB)

// ---------- helpers ----------
__device__ __forceinline__ void gl_lds16(const _Float16* g, _Float16* l) {
  __builtin_amdgcn_global_load_lds(
      (const __attribute__((address_space(1))) void*)g,
      (__attribute__((address_space(3))) void*)l, 16, 0, 0);
}
__device__ __forceinline__ void gl_lds16c(const char* g, char* l) {
  __builtin_amdgcn_global_load_lds(
      (const __attribute__((address_space(1))) void*)g,
      (__attribute__((address_space(3))) void*)l, 16, 0, 0);
}

struct GeluP { float scale1, bintg, cintg, shiftint, s_out; };

__device__ __forceinline__ GeluP gelu_params(float max1) {
  GeluP p;
  p.scale1 = fmaxf(max1, 1e-8f) / 127.0f;
  float se = p.scale1 / 1.4142f;
  p.bintg = floorf(-1.769f / se);
  p.cintg = floorf(((float)(1.0 / -0.2888)) / (se * se));
  float se2 = ((se * se) * -0.2888f) * 16384.0f;
  p.shiftint = floorf(1.0f / se2);
  p.s_out = (p.scale1 * se2) * 0.5f;
  return p;
}

__device__ __forceinline__ float gelu_val(const GeluP& p, float qf) {
  float sg = (qf > 0.f) ? 1.f : ((qf < 0.f) ? -1.f : 0.f);
  float aq = fminf(fabsf(qf), -p.bintg);
  float t = aq + p.bintg;
  float y = sg * (t * t + p.cintg);
  float yf = floorf(y * (1.0f / 16384.0f));
  return (qf * (yf + p.shiftint)) * p.s_out;
}

// ---------- k12: weight quantization + x quantization (merged) ----------
__global__ __launch_bounds__(256)
void k12_prep(const float* __restrict__ W1, const float* __restrict__ b1,
              const float* __restrict__ W2, const float* __restrict__ x,
              const float* __restrict__ sxp,
              _Float16* __restrict__ wq1, char* __restrict__ wq2i,
              float* __restrict__ wscale2, float* __restrict__ bint1,
              float* __restrict__ bscale1, _Float16* __restrict__ xq,
              unsigned* __restrict__ wsu)
{
  if (blockIdx.x == 0 && threadIdx.x == 0) { wsu[0] = 0u; wsu[1] = 0u; wsu[2] = 0u; }
  if (blockIdx.x < 960) {
    int w = blockIdx.x * 4 + (threadIdx.x >> 6);   // one wave per output row
    int lane = threadIdx.x & 63;
    if (w < H_DIM) {            // W1: 3072 rows, K=768
      const float* row = W1 + (size_t)w * D_DIM;
      f32x4 v[3]; float m = 0.f;
#pragma unroll
      for (int t = 0; t < 3; t++) {
        v[t] = *(const f32x4*)(row + t * 256 + lane * 4);
#pragma unroll
        for (int j = 0; j < 4; j++) m = fmaxf(m, fabsf(v[t][j]));
      }
#pragma unroll
      for (int off = 32; off >= 1; off >>= 1) m = fmaxf(m, __shfl_xor(m, off));
      float wsc = fmaxf(m, 1e-8f) / 127.0f;
      _Float16* orow = wq1 + (size_t)w * D_DIM;
#pragma unroll
      for (int t = 0; t < 3; t++) {
        half4v h;
#pragma unroll
        for (int j = 0; j < 4; j++) {
          float q = fminf(fmaxf(rintf(v[t][j] / wsc), -128.f), 127.f);
          h[j] = (_Float16)q;
        }
        *(half4v*)(orow + t * 256 + lane * 4) = h;
      }
      if (lane == 0) {
        float bs = wsc * sxp[0];
        bint1[w] = rintf(b1[w] / bs);
        bscale1[w] = bs;
      }
    } else {                    // W2: 768 rows, K=3072 -> int8
      int o = w - H_DIM;
      const float* row = W2 + (size_t)o * H_DIM;
      f32x4 v[12]; float m = 0.f;
#pragma unroll
      for (int t = 0; t < 12; t++) {
        v[t] = *(const f32x4*)(row + t * 256 + lane * 4);
#pragma unroll
        for (int j = 0; j < 4; j++) m = fmaxf(m, fabsf(v[t][j]));
      }
#pragma unroll
      for (int off = 32; off >= 1; off >>= 1) m = fmaxf(m, __shfl_xor(m, off));
      float wsc = fmaxf(m, 1e-8f) / 127.0f;
      unsigned* orow = (unsigned*)(wq2i + (size_t)o * H_DIM);
#pragma unroll
      for (int t = 0; t < 12; t++) {
        unsigned pk = 0;
#pragma unroll
        for (int j = 0; j < 4; j++) {
          float q = fminf(fmaxf(rintf(v[t][j] / wsc), -128.f), 127.f);
          pk |= ((unsigned)(unsigned char)(char)(int)q) << (8 * j);
        }
        orow[t * 64 + lane] = pk;
      }
      if (lane == 0) wscale2[o] = wsc;
    }
  } else {                      // x -> f16 ints: 1024 blocks, grid-stride
    float sx = sxp[0];
    const int n4 = (M_DIM * D_DIM) / 4;
    const int stride = 1024 * 256;
    for (int i = (blockIdx.x - 960) * 256 + threadIdx.x; i < n4; i += stride) {
      f32x4 v = ((const f32x4*)x)[i];
      half4v h;
#pragma unroll
      for (int j = 0; j < 4; j++) h[j] = (_Float16)(v[j] / sx);
      ((half4v*)xq)[i] = h;
    }
  }
}

// ---------- fc1 GEMM, deep pipeline (round-4 config) ----------
// 128x256 tile, BK=32, 8 waves (2m x 4n, 64x64 each), triple-buffered LDS,
// counted vmcnt, chunk-XOR swizzle, setprio, two acc-quadrant phases.
#define SLOT_A 4096               // halfs: 128 rows x 32
#define SLOT_B 8192               // halfs: 256 rows x 32
#define SLOT_SZ (SLOT_A + SLOT_B)

__global__ __launch_bounds__(512)
void gemm_f16_dp(const _Float16* __restrict__ A, const _Float16* __restrict__ B,
                 const float* __restrict__ bint, const float* __restrict__ bscale,
                 float* __restrict__ C, unsigned* __restrict__ maxw, int N, int K)
{
  __shared__ _Float16 lds[3 * SLOT_SZ];
  __shared__ float wred[8];
  const int tid = threadIdx.x;
  const int wid = tid >> 6;            // 0..7
  const int lane = tid & 63;
  const int m0 = blockIdx.x * 128;
  const int n0 = blockIdx.y * 256;
  const int wm = wid >> 2;             // 0..1
  const int wn = wid & 3;              // 0..3

  const int sr = lane >> 2;            // row within 16-row group
  const int sc = lane & 3;             // 16B chunk within 64B row
  const int ra  = wid * 16 + sr;
  const int csa = sc ^ ((ra >> 1) & 3);
  const int rb  = wid * 16 + sr;
  const int csb = sc ^ ((rb >> 1) & 3);
  const _Float16* pa  = A + (size_t)(m0 + ra) * K + csa * 8;
  const _Float16* pb0 = B + (size_t)(n0 + rb) * K + csb * 8;
  const _Float16* pb1 = B + (size_t)(n0 + rb + 128) * K + csb * 8;
  _Float16* const da  = lds;
  _Float16* const db0 = lds + SLOT_A;
  _Float16* const db1 = lds + SLOT_A + 4096;

#define STAGE_DP(t, s) do {                                                  \
    const int _o = (s) * SLOT_SZ + wid * 512;                                \
    gl_lds16(pa  + (size_t)(t) * 32, da  + _o);                              \
    gl_lds16(pb0 + (size_t)(t) * 32, db0 + _o);                              \
    gl_lds16(pb1 + (size_t)(t) * 32, db1 + _o);                              \
  } while (0)

  int aoff[4], boff[4];
  const int ks = lane >> 4;
#pragma unroll
  for (int f = 0; f < 4; f++) {
    int r = wm * 64 + f * 16 + (lane & 15);
    aoff[f] = r * 64 + ((ks ^ ((r >> 1) & 3)) * 16);
    int rn = wn * 64 + f * 16 + (lane & 15);
    boff[f] = SLOT_A * 2 + rn * 64 + ((ks ^ ((rn >> 1) & 3)) * 16);
  }

  f32x4 acc[4][4];
#pragma unroll
  for (int i = 0; i < 4; i++)
#pragma unroll
    for (int j = 0; j < 4; j++) acc[i][j] = (f32x4){0.f, 0.f, 0.f, 0.f};

  const int nt = K / 32;
  STAGE_DP(0, 0);
  STAGE_DP(1, 1);
  for (int t = 0; t < nt; ++t) {
    const int s = t % 3;
    if (t + 1 < nt) asm volatile("s_waitcnt vmcnt(3)" ::: "memory");
    else            asm volatile("s_waitcnt vmcnt(0)" ::: "memory");
    asm volatile("s_barrier" ::: "memory");
    if (t + 2 < nt) STAGE_DP(t + 2, (t + 2) % 3);
    const char* sb = (const char*)(lds + s * SLOT_SZ);
    half8 a[4], b01[2], b23[2];
#pragma unroll
    for (int f = 0; f < 4; f++) a[f] = *(const half8*)(sb + aoff[f]);
    b01[0] = *(const half8*)(sb + boff[0]);
    b01[1] = *(const half8*)(sb + boff[1]);
    __builtin_amdgcn_s_setprio(1);
#pragma unroll
    for (int i = 0; i < 4; i++)
#pragma unroll
      for (int j = 0; j < 2; j++)
        acc[i][j] = __builtin_amdgcn_mfma_f32_16x16x32_f16(a[i], b01[j], acc[i][j], 0, 0, 0);
    __builtin_amdgcn_s_setprio(0);
    b23[0] = *(const half8*)(sb + boff[2]);
    b23[1] = *(const half8*)(sb + boff[3]);
    __builtin_amdgcn_s_setprio(1);
#pragma unroll
    for (int i = 0; i < 4; i++)
#pragma unroll
      for (int j = 0; j < 2; j++)
        acc[i][j + 2] = __builtin_amdgcn_mfma_f32_16x16x32_f16(a[i], b23[j], acc[i][j + 2], 0, 0, 0);
    __builtin_amdgcn_s_setprio(0);
  }
#undef STAGE_DP

  float tmax = 0.f;
  const int orow0 = m0 + wm * 64 + (lane >> 4) * 4;
  const int ocol0 = n0 + wn * 64 + (lane & 15);
#pragma unroll
  for (int j = 0; j < 4; j++) {
    const int col = ocol0 + j * 16;
    const float bi = bint[col];
    const float bs = bscale[col];
#pragma unroll
    for (int i = 0; i < 4; i++) {
#pragma unroll
      for (int e = 0; e < 4; e++) {
        const int rowm = orow0 + i * 16 + e;
        float v = (acc[i][j][e] + bi) * bs;
        C[(size_t)rowm * N + col] = v;
        tmax = fmaxf(tmax, fabsf(v));
      }
    }
  }
#pragma unroll
  for (int off = 32; off >= 1; off >>= 1) tmax = fmaxf(tmax, __shfl_xor(tmax, off));
  if (lane == 0) wred[wid] = tmax;
  __syncthreads();
  if (tid == 0) {
    float bm = 0.f;
#pragma unroll
    for (int i = 0; i < 8; i++) bm = fmaxf(bm, wred[i]);
    atomicMax(maxw, __float_as_uint(bm));
  }
}

// ---------- k4: 8-bit requant of h1 + inline IntGELU for max2 ----------
__global__ __launch_bounds__(256)
void k4_gelu(const float* __restrict__ h1, const unsigned* __restrict__ wsu,
             char* __restrict__ q1, unsigned* __restrict__ maxw, int n4)
{
  GeluP p = gelu_params(__uint_as_float(wsu[0]));
  float tmax = 0.f;
  int stride = gridDim.x * blockDim.x;
  for (int i = blockIdx.x * blockDim.x + threadIdx.x; i < n4; i += stride) {
    f32x4 h = ((const f32x4*)h1)[i];
    unsigned pack = 0;
#pragma unroll
    for (int j = 0; j < 4; j++) {
      float qf = fminf(fmaxf(rintf(h[j] / p.scale1), -128.f), 127.f);
      tmax = fmaxf(tmax, fabsf(gelu_val(p, qf)));
      pack |= ((unsigned)(unsigned char)(char)(int)qf) << (8 * j);
    }
    ((unsigned*)q1)[i] = pack;
  }
#pragma unroll
  for (int off = 32; off >= 1; off >>= 1) tmax = fmaxf(tmax, __shfl_xor(tmax, off));
  __shared__ float wred[4];
  int wid = threadIdx.x >> 6;
  if ((threadIdx.x & 63) == 0) wred[wid] = tmax;
  __syncthreads();
  if (threadIdx.x == 0) {
    float bm = fmaxf(fmaxf(wred[0], wred[1]), fmaxf(wred[2], wred[3]));
    atomicMax(maxw, __float_as_uint(bm));
  }
}

// ---------- fc2 GEMM: int8 MFMA, LUT-fused A (q1 -> q2 in-register) ----------
// 64x128 tile, BK=64, 4 waves (2x2 of 32x64), triple-buffered 36KB LDS,
// counted vmcnt, B via pre-swizzled gl_lds, A reg-staged + LUT + swizzled ds_write,
// bias computed inline in epilogue (k5, k6 eliminated).
#define I8L_SLOT 12288   // bytes: A 64x64 (4096) + B 128x64 (8192)

__global__ __launch_bounds__(256)
void gemm_i8_lut(const char* __restrict__ q1, const char* __restrict__ B,
                 const unsigned* __restrict__ wsu, const float* __restrict__ wscale2,
                 const float* __restrict__ b2, float* __restrict__ C,
                 unsigned* __restrict__ maxw, int N, int K)
{
  __shared__ char lds[3 * I8L_SLOT];
  __shared__ float wred[4];
  const int tid = threadIdx.x;
  const int wid = tid >> 6;
  const int lane = tid & 63;
  const int m0 = blockIdx.x * 64;
  const int n0 = blockIdx.y * 128;
  const int wm = wid >> 1;             // 0..1
  const int wn = wid & 1;              // 0..1

  // ---- build q1->q2 LUT: lane L holds codes 4L-128 .. 4L-125 (one u32) ----
  GeluP p = gelu_params(__uint_as_float(wsu[0]));
  const float scale2 = fmaxf(__uint_as_float(wsu[1]), 1e-8f) / 127.0f;
  unsigned lutw = 0;
#pragma unroll
  for (int j = 0; j < 4; j++) {
    float qf = (float)(lane * 4 + j - 128);
    float g = gelu_val(p, qf);
    float q2f = fminf(fmaxf(rintf(g / scale2), -128.f), 127.f);
    lutw |= ((unsigned)(unsigned char)(char)(int)q2f) << (8 * j);
  }

  // ---- staging addresses ----
  const int sr = tid >> 2;             // 0..63
  const int sc = tid & 3;              // 16B chunk in 64B row
  const int csw = sc ^ ((sr >> 1) & 3);
  const char* paq = q1 + (size_t)(m0 + sr) * K + sc * 16;          // A: linear source
  const int awaddr = sr * 64 + csw * 16;                           // A: swizzled LDS dest
  const char* pb0 = B + (size_t)(n0 + sr) * K + csw * 16;          // B: pre-swizzled source
  const char* pb1 = B + (size_t)(n0 + 64 + sr) * K + csw * 16;

#define STAGE_B(t, s) do {                                                   \
    char* const base = lds + (s) * I8L_SLOT + 4096 + wid * 1024;             \
    gl_lds16c(pb0 + (size_t)(t) * 64, base);                                 \
    gl_lds16c(pb1 + (size_t)(t) * 64, base + 4096);                          \
  } while (0)

  int aoff[2], boff[4];
  const int ks = lane >> 4;
#pragma unroll
  for (int f = 0; f < 2; f++) {
    int r = wm * 32 + f * 16 + (lane & 15);
    aoff[f] = r * 64 + ((ks ^ ((r >> 1) & 3)) * 16);
  }
#pragma unroll
  for (int f = 0; f < 4; f++) {
    int rn = wn * 64 + f * 16 + (lane & 15);
    boff[f] = 4096 + rn * 64 + ((ks ^ ((rn >> 1) & 3)) * 16);
  }

  int4v acc[2][4];
#pragma unroll
  for (int i = 0; i < 2; i++)
#pragma unroll
    for (int j = 0; j < 4; j++) acc[i][j] = (int4v){0, 0, 0, 0};

  const int nt = K / 64;               // 48

  // prologue: A(0),B(0); A(1),B(1)
  uint4 ar0 = *(const uint4*)(paq);
  STAGE_B(0, 0);
  uint4 arn = *(const uint4*)(paq + 64);
  STAGE_B(1, 1);
  asm volatile("s_waitcnt vmcnt(3)" ::: "memory");   // A(0)+B(0) returned
  {
    uint4 aw;
    unsigned* s = (unsigned*)&ar0; unsigned* d = (unsigned*)&aw;
#pragma unroll
    for (int w = 0; w < 4; w++) {
      unsigned r = 0;
#pragma unroll
      for (int j = 0; j < 4; j++) {
        int idx = ((int)(signed char)(s[w] >> (8 * j))) + 128;
        unsigned wd = (unsigned)__shfl((int)lutw, idx >> 2, 64);
        r |= ((wd >> ((idx & 3) * 8)) & 0xFFu) << (8 * j);
      }
      d[w] = r;
    }
    *(uint4*)(lds + awaddr) = aw;      // slot 0
  }

  for (int t = 0; t < nt; ++t) {
    const int s = t % 3;
    if (t + 1 < nt) asm volatile("s_waitcnt vmcnt(2)" ::: "memory");  // A(t+1)+tile t done
    else            asm volatile("s_waitcnt vmcnt(0)" ::: "memory");
    asm volatile("s_waitcnt lgkmcnt(0)" ::: "memory");
    asm volatile("s_barrier" ::: "memory");
    if (t + 1 < nt) {                  // LUT-map A(t+1), write to its slot
      uint4 aw;
      unsigned* sp = (unsigned*)&arn; unsigned* d = (unsigned*)&aw;
#pragma unroll
      for (int w = 0; w < 4; w++) {
        unsigned r = 0;
#pragma unroll
        for (int j = 0; j < 4; j++) {
          int idx = ((int)(signed char)(sp[w] >> (8 * j))) + 128;
          unsigned wd = (unsigned)__shfl((int)lutw, idx >> 2, 64);
          r |= ((wd >> ((idx & 3) * 8)) & 0xFFu) << (8 * j);
        }
        d[w] = r;
      }
      *(uint4*)(lds + ((t + 1) % 3) * I8L_SLOT + awaddr) = aw;
    }
    if (t + 2 < nt) {
      arn = *(const uint4*)(paq + (size_t)(t + 2) * 64);
      STAGE_B(t + 2, (t + 2) % 3);
    }
    const char* sb = lds + s * I8L_SLOT;
    int4v a[2], b01[2], b23[2];
#pragma unroll
    for (int f = 0; f < 2; f++) a[f] = *(const int4v*)(sb + aoff[f]);
    b01[0] = *(const int4v*)(sb + boff[0]);
    b01[1] = *(const int4v*)(sb + boff[1]);
    __builtin_amdgcn_s_setprio(1);
#pragma unroll
    for (int i = 0; i < 2; i++)
#pragma unroll
      for (int j = 0; j < 2; j++)
        acc[i][j] = __builtin_amdgcn_mfma_i32_16x16x64_i8(a[i], b01[j], acc[i][j], 0, 0, 0);
    __builtin_amdgcn_s_setprio(0);
    b23[0] = *(const int4v*)(sb + boff[2]);
    b23[1] = *(const int4v*)(sb + boff[3]);
    __builtin_amdgcn_s_setprio(1);
#pragma unroll
    for (int i = 0; i < 2; i++)
#pragma unroll
      for (int j = 0; j < 2; j++)
        acc[i][j + 2] = __builtin_amdgcn_mfma_i32_16x16x64_i8(a[i], b23[j], acc[i][j + 2], 0, 0, 0);
    __builtin_amdgcn_s_setprio(0);
  }
#undef STAGE_B

  float tmax = 0.f;
  const int orow0 = m0 + wm * 32 + (lane >> 4) * 4;
  const int ocol0 = n0 + wn * 64 + (lane & 15);
#pragma unroll
  for (int j = 0; j < 4; j++) {
    const int col = ocol0 + j * 16;
    const float bs = wscale2[col] * scale2;      // fused k6
    const float bi = rintf(b2[col] / bs);
#pragma unroll
    for (int i = 0; i < 2; i++) {
#pragma unroll
      for (int e = 0; e < 4; e++) {
        const int rowm = orow0 + i * 16 + e;
        float v = ((float)acc[i][j][e] + bi) * bs;
        C[(size_t)rowm * N + col] = v;
        tmax = fmaxf(tmax, fabsf(v));
      }
    }
  }
#pragma unroll
  for (int off = 32; off >= 1; off >>= 1) tmax = fmaxf(tmax, __shfl_xor(tmax, off));
  if (lane == 0) wred[wid] = tmax;
  __syncthreads();
  if (tid == 0) {
    float bm = fmaxf(fmaxf(wred[0], wred[1]), fmaxf(wred[2], wred[3]));
    atomicMax(maxw, __float_as_uint(bm));
  }
}

// ---------- k7: 16-bit requant of h2 -> output (+ scale scalar) ----------
__global__ __launch_bounds__(256)
void k7_final(const float* __restrict__ h2, const unsigned* __restrict__ wsu,
              float* __restrict__ out, int n4, int ntot)
{
  float scale16 = fmaxf(__uint_as_float(wsu[2]), 1e-8f) / 32767.0f;
  int stride = gridDim.x * blockDim.x;
  for (int i = blockIdx.x * blockDim.x + threadIdx.x; i < n4; i += stride) {
    f32x4 v = ((const f32x4*)h2)[i];
    f32x4 o;
#pragma unroll
    for (int j = 0; j < 4; j++) {
      float q = fminf(fmaxf(rintf(v[j] / scale16), -32768.f), 32767.f);
      o[j] = q * scale16;
    }
    ((f32x4*)out)[i] = o;
  }
  if (blockIdx.x == 0 && threadIdx.x == 0) out[ntot] = scale16;
}

extern "C" void kernel_launch(void* const* d_in, const int* in_sizes, int n_in,
                              void* d_out, int out_size, void* d_ws, size_t ws_size,
                              hipStream_t stream)
{
  (void)in_sizes; (void)n_in; (void)out_size; (void)ws_size;
  const float* x  = (const float*)d_in[0];
  const float* sx = (const float*)d_in[1];
  const float* W1 = (const float*)d_in[2];
  const float* b1 = (const float*)d_in[3];
  const float* W2 = (const float*)d_in[4];
  const float* b2 = (const float*)d_in[5];
  float* out = (float*)d_out;
  char* ws = (char*)d_ws;

  unsigned* wsu   = (unsigned*)ws;                 // [0]=max1 [1]=max2 [2]=max3
  float* wscale2  = (float*)(ws + WS_WSCALE2);
  float* bint1    = (float*)(ws + WS_BINT1);
  float* bscale1  = (float*)(ws + WS_BSCALE1);
  _Float16* xq    = (_Float16*)(ws + WS_XQ);
  _Float16* wq1   = (_Float16*)(ws + WS_WQ1);
  char* wq2i      = (char*)(ws + WS_WQ2I);
  float* h1       = (float*)(ws + WS_H1);
  float* h2       = (float*)(ws + WS_H2);
  char* q1        = (char*)(ws + WS_Q1);

  k12_prep<<<dim3(1984), dim3(256), 0, stream>>>(W1, b1, W2, x, sx, wq1, wq2i,
                                                 wscale2, bint1, bscale1, xq, wsu);
  gemm_f16_dp<<<dim3(64, 12), dim3(512), 0, stream>>>(xq, wq1, bint1, bscale1, h1, wsu + 0, H_DIM, D_DIM);
  k4_gelu<<<dim3(2048), dim3(256), 0, stream>>>(h1, wsu, q1, wsu + 1, (M_DIM * H_DIM) / 4);
  gemm_i8_lut<<<dim3(128, 6), dim3(256), 0, stream>>>(q1, wq2i, wsu, wscale2, b2, h2, wsu + 2, D_DIM, H_DIM);
  k7_final<<<dim3(2048), dim3(256), 0, stream>>>(h2, wsu, out, (M_DIM * D_DIM) / 4, M_DIM * D_DIM);
}